// Round 1
// baseline (255.658 us; speedup 1.0000x reference)
//
#include <hip/hip_runtime.h>

#define NB 4096     // batch
#define ND 512      // dim

typedef __bf16 bf16x8 __attribute__((ext_vector_type(8)));
typedef unsigned short u16x8 __attribute__((ext_vector_type(8)));
typedef float f32x4 __attribute__((ext_vector_type(4)));

__device__ inline unsigned short f2bf(float f){
  unsigned u = __float_as_uint(f);
  u += 0x7FFFu + ((u >> 16) & 1u);      // round-to-nearest-even
  return (unsigned short)(u >> 16);
}

// monotone float <-> uint mapping for atomicMin/Max on floats
__device__ inline unsigned encf(float f){
  unsigned u = __float_as_uint(f);
  return (u & 0x80000000u) ? ~u : (u | 0x80000000u);
}
__device__ inline float decf(unsigned u){
  unsigned v = (u & 0x80000000u) ? (u ^ 0x80000000u) : ~u;
  return __uint_as_float(v);
}

__global__ __launch_bounds__(256) void init_stats(float* row_sum, unsigned* row_minpos,
                                                  unsigned* row_maxneg, float* row_sigma,
                                                  float* row_fp, float* row_fn){
  int r = blockIdx.x * 256 + threadIdx.x;
  if (r < NB){
    row_sum[r] = 0.f;
    row_minpos[r] = 0xFFFFFFFFu;   // "no positive seen"
    row_maxneg[r] = 0u;            // "no negative seen"
    row_sigma[r] = 0.f;
    row_fp[r] = 0.f;
    row_fn[r] = 0.f;
  }
}

__global__ __launch_bounds__(256) void convert_bf16(const float* feats, unsigned short* fb){
  size_t idx = (size_t)blockIdx.x * 256 + threadIdx.x;  // group of 8 elements
  const float4* p = (const float4*)(feats + idx * 8);
  float4 x0 = p[0], x1 = p[1];
  u16x8 v;
  v[0]=f2bf(x0.x); v[1]=f2bf(x0.y); v[2]=f2bf(x0.z); v[3]=f2bf(x0.w);
  v[4]=f2bf(x1.x); v[5]=f2bf(x1.y); v[6]=f2bf(x1.z); v[7]=f2bf(x1.w);
  *(u16x8*)(fb + idx * 8) = v;
}

// Tile GEMM over sim = F F^T (bf16 in, fp32 acc), 64x64 per block, fused row reductions.
// PASS 1: row_sum (+=), row_minpos (atomicMin over same-class & sim<1-eps),
//         row_maxneg (atomicMax over diff-class).
// PASS 2: row_sigma (+= (v-mean_)^2 over neg), row_fp (+= exp(-(v-.5)*2) over pp),
//         row_fn (+= exp((v-.5)*40) over nm).
template<int PASS>
__global__ __launch_bounds__(256) void dbml_gemm(const unsigned short* fb, const int* labels,
                                                 float* row_sum, unsigned* row_minpos,
                                                 unsigned* row_maxneg, float* row_sigma,
                                                 float* row_fp, float* row_fn){
  __shared__ unsigned short As[64][40];   // +8 pad: 80B row stride -> 2-way LDS aliasing (free)
  __shared__ unsigned short Bs[64][40];
  __shared__ int labR[64], labC[64];
  __shared__ float sMean[64], sTpp[64], sTnm[64];

  const int tid  = threadIdx.x;
  const int bx   = blockIdx.x;   // col block
  const int by   = blockIdx.y;   // row block
  const int lane = tid & 63;
  const int wave = tid >> 6;
  const int m0   = (wave >> 1) * 32;   // wave's row quadrant in tile
  const int n0   = (wave & 1) * 32;    // wave's col quadrant
  const int quad = lane >> 4;
  const int l15  = lane & 15;

  if (tid < 64){
    labR[tid] = labels[by*64 + tid];
    if (PASS == 2){
      int R = by*64 + tid;
      unsigned up = row_minpos[R], un = row_maxneg[R];
      float mp = (up == 0xFFFFFFFFu) ? 1.0e9f : decf(up);   // BIG like reference
      float mn = (un == 0u)          ? -1.0e9f : decf(un);
      sMean[tid] = (row_sum[R] * (1.0f/(float)NB) + 0.5f*(mp+mn)) * 0.5f;
      sTpp[tid]  = mn + 0.1f;   // pp: sim < max_neg + MARGIN
      sTnm[tid]  = mp - 0.1f;   // nm: sim > min_pos - MARGIN
    }
  } else if (tid < 128){
    labC[tid-64] = labels[bx*64 + (tid-64)];
  }

  // staging assignment: each thread stages one 8-elem (16B) chunk per tile
  const int sr = tid >> 2;          // 0..63
  const int sc = (tid & 3) * 8;     // 0,8,16,24
  const unsigned short* aseg = fb + (size_t)(by*64 + sr) * ND + sc;
  const unsigned short* bseg = fb + (size_t)(bx*64 + sr) * ND + sc;

  f32x4 acc[2][2];
#pragma unroll
  for (int i=0;i<2;++i)
#pragma unroll
    for (int j=0;j<2;++j) acc[i][j] = (f32x4){0.f,0.f,0.f,0.f};

  for (int k0 = 0; k0 < ND; k0 += 32){
    __syncthreads();   // protect previous iteration's LDS reads (first iter: label/stat writes)
    *(u16x8*)&As[sr][sc] = *(const u16x8*)(aseg + k0);
    *(u16x8*)&Bs[sr][sc] = *(const u16x8*)(bseg + k0);
    __syncthreads();

    bf16x8 af[2], bfr[2];
#pragma unroll
    for (int s = 0; s < 2; ++s){
      af[s]  = __builtin_bit_cast(bf16x8, *(const u16x8*)&As[m0 + s*16 + l15][quad*8]);
      bfr[s] = __builtin_bit_cast(bf16x8, *(const u16x8*)&Bs[n0 + s*16 + l15][quad*8]);
    }
#pragma unroll
    for (int sm=0;sm<2;++sm)
#pragma unroll
      for (int sn=0;sn<2;++sn)
        acc[sm][sn] = __builtin_amdgcn_mfma_f32_16x16x32_bf16(af[sm], bfr[sn], acc[sm][sn], 0, 0, 0);
  }

  // epilogue: per-row fused reductions.
  // C/D layout: col = lane&15, row = quad*4 + reg (within 16x16 subtile)
  const int lc0 = labC[n0 + l15];
  const int lc1 = labC[n0 + 16 + l15];

#pragma unroll
  for (int sm=0;sm<2;++sm){
#pragma unroll
    for (int reg=0;reg<4;++reg){
      const int rl = m0 + sm*16 + quad*4 + reg;   // local row in tile
      const int lr = labR[rl];
      const float v0 = acc[sm][0][reg];
      const float v1 = acc[sm][1][reg];

      if (PASS == 1){
        float s = v0 + v1;
        float mp = 3.0e38f, mn = -3.0e38f;
        if (lr == lc0){ if (v0 < 0.99999f) mp = v0; } else { mn = v0; }
        if (lr == lc1){ if (v1 < 0.99999f) mp = fminf(mp, v1); } else { mn = fmaxf(mn, v1); }
#pragma unroll
        for (int o=1;o<16;o<<=1){
          s  += __shfl_xor(s, o, 64);
          mp  = fminf(mp, __shfl_xor(mp, o, 64));
          mn  = fmaxf(mn, __shfl_xor(mn, o, 64));
        }
        if (l15 == 0){
          int R = by*64 + rl;
          atomicAdd(&row_sum[R], s);
          if (mp <  1.0e38f) atomicMin(&row_minpos[R], encf(mp));
          if (mn > -1.0e38f) atomicMax(&row_maxneg[R], encf(mn));
        }
      } else {
        const float mean_ = sMean[rl], tpp = sTpp[rl], tnm = sTnm[rl];
        float sg = 0.f, fps = 0.f, fns = 0.f;
        if (lr != lc0){
          float d = v0 - mean_; sg += d*d;
          if (v0 > tnm) fns += __expf((v0 - 0.5f) * 40.0f);
        } else if (v0 < 0.99999f && v0 < tpp){
          fps += __expf(-(v0 - 0.5f) * 2.0f);
        }
        if (lr != lc1){
          float d = v1 - mean_; sg += d*d;
          if (v1 > tnm) fns += __expf((v1 - 0.5f) * 40.0f);
        } else if (v1 < 0.99999f && v1 < tpp){
          fps += __expf(-(v1 - 0.5f) * 2.0f);
        }
#pragma unroll
        for (int o=1;o<16;o<<=1){
          sg  += __shfl_xor(sg,  o, 64);
          fps += __shfl_xor(fps, o, 64);
          fns += __shfl_xor(fns, o, 64);
        }
        if (l15 == 0){
          int R = by*64 + rl;
          atomicAdd(&row_sigma[R], sg);
          atomicAdd(&row_fp[R], fps);
          atomicAdd(&row_fn[R], fns);
        }
      }
    }
  }
}

__global__ __launch_bounds__(256) void finalize(const unsigned* row_minpos, const unsigned* row_maxneg,
                                                const float* row_sigma, const float* row_fp,
                                                const float* row_fn, float* out){
  const int tid = threadIdx.x;
  float local = 0.f;
  for (int r = tid; r < NB; r += 256){
    bool has_pos = (row_minpos[r] != 0xFFFFFFFFu);
    bool has_neg = (row_maxneg[r] != 0u);
    float fps = row_fp[r], fns = row_fn[r];
    if (has_pos && has_neg && fps > 0.f && fns > 0.f){
      local += logf(1.f + fps) + logf(1.f + fns) + 0.1f * row_sigma[r];
    }
  }
#pragma unroll
  for (int o=1;o<64;o<<=1) local += __shfl_xor(local, o, 64);
  __shared__ float red[4];
  if ((tid & 63) == 0) red[tid >> 6] = local;
  __syncthreads();
  if (tid == 0) out[0] = (red[0] + red[1] + red[2] + red[3]) * (1.0f/(float)NB);
}

extern "C" void kernel_launch(void* const* d_in, const int* in_sizes, int n_in,
                              void* d_out, int out_size, void* d_ws, size_t ws_size,
                              hipStream_t stream) {
  (void)in_sizes; (void)n_in; (void)out_size; (void)ws_size;
  const float* feats  = (const float*)d_in[0];
  const int*   labels = (const int*)d_in[1];
  float* out = (float*)d_out;

  // ws layout: 6 row-stat arrays (96KB) then bf16 feats (4MB)
  float*    row_sum    = (float*)d_ws;
  unsigned* row_minpos = (unsigned*)(row_sum + NB);
  unsigned* row_maxneg = row_minpos + NB;
  float*    row_sigma  = (float*)(row_maxneg + NB);
  float*    row_fp     = row_sigma + NB;
  float*    row_fn     = row_fp + NB;
  unsigned short* fb   = (unsigned short*)(row_fn + NB);

  init_stats<<<dim3((NB+255)/256), dim3(256), 0, stream>>>(row_sum, row_minpos, row_maxneg,
                                                           row_sigma, row_fp, row_fn);
  convert_bf16<<<dim3((NB*ND/8)/256), dim3(256), 0, stream>>>(feats, fb);

  dim3 grid(NB/64, NB/64);
  dbml_gemm<1><<<grid, dim3(256), 0, stream>>>(fb, labels, row_sum, row_minpos, row_maxneg,
                                               row_sigma, row_fp, row_fn);
  dbml_gemm<2><<<grid, dim3(256), 0, stream>>>(fb, labels, row_sum, row_minpos, row_maxneg,
                                               row_sigma, row_fp, row_fn);
  finalize<<<1, 256, 0, stream>>>(row_minpos, row_maxneg, row_sigma, row_fp, row_fn, out);
}

// Round 2
// 164.325 us; speedup vs baseline: 1.5558x; 1.5558x over previous
//
#include <hip/hip_runtime.h>

#define NB 4096     // batch
#define ND 512      // dim

typedef __bf16 bf16x8 __attribute__((ext_vector_type(8)));
typedef unsigned short u16x8 __attribute__((ext_vector_type(8)));
typedef float f32x4 __attribute__((ext_vector_type(4)));

__device__ inline unsigned short f2bf(float f){
  unsigned u = __float_as_uint(f);
  u += 0x7FFFu + ((u >> 16) & 1u);      // round-to-nearest-even
  return (unsigned short)(u >> 16);
}

// monotone float <-> uint mapping for atomicMin/Max on floats
__device__ inline unsigned encf(float f){
  unsigned u = __float_as_uint(f);
  return (u & 0x80000000u) ? ~u : (u | 0x80000000u);
}
__device__ inline float decf(unsigned u){
  unsigned v = (u & 0x80000000u) ? (u ^ 0x80000000u) : ~u;
  return __uint_as_float(v);
}

// async global->LDS, 16B per lane. LDS dest = wave-uniform base + lane*16.
__device__ inline void gl2lds16(const unsigned short* g, unsigned short* l){
  __builtin_amdgcn_global_load_lds(
      (const __attribute__((address_space(1))) unsigned int*)g,
      (__attribute__((address_space(3))) unsigned int*)l, 16, 0, 0);
}

// fused: feats fp32 -> bf16, plus stat-array init in the first 16 blocks
__global__ __launch_bounds__(256) void convert_init(const float* feats, unsigned short* fb,
                                                    float* row_sum, unsigned* row_minpos,
                                                    unsigned* row_maxneg, float* row_sigma,
                                                    float* row_fp, float* row_fn){
  size_t idx = (size_t)blockIdx.x * 256 + threadIdx.x;  // group of 8 elements
  const float4* p = (const float4*)(feats + idx * 8);
  float4 x0 = p[0], x1 = p[1];
  u16x8 v;
  v[0]=f2bf(x0.x); v[1]=f2bf(x0.y); v[2]=f2bf(x0.z); v[3]=f2bf(x0.w);
  v[4]=f2bf(x1.x); v[5]=f2bf(x1.y); v[6]=f2bf(x1.z); v[7]=f2bf(x1.w);
  *(u16x8*)(fb + idx * 8) = v;

  if (blockIdx.x < 16){
    int r = blockIdx.x * 256 + threadIdx.x;   // 16*256 == NB
    row_sum[r] = 0.f;
    row_minpos[r] = 0xFFFFFFFFu;   // "no positive seen"
    row_maxneg[r] = 0u;            // "no negative seen"
    row_sigma[r] = 0.f;
    row_fp[r] = 0.f;
    row_fn[r] = 0.f;
  }
}

// 128x128 tile / 4 waves / 4x4 16x16x32-MFMA fragments per wave / BK=32.
// Staging via global_load_lds width-16 (m97 structure). Fused row reductions.
// PASS 1: row_sum, row_minpos (same-class & sim<1-eps), row_maxneg (diff-class).
// PASS 2: row_sigma, row_fp (pp), row_fn (nm).
template<int PASS>
__global__ __launch_bounds__(256) void dbml_gemm(const unsigned short* fb, const int* labels,
                                                 float* row_sum, unsigned* row_minpos,
                                                 unsigned* row_maxneg, float* row_sigma,
                                                 float* row_fp, float* row_fn){
  // unpadded 32-short (64B) row stride: b128 banking is phase-uniform
  __shared__ unsigned short As[128*32];
  __shared__ unsigned short Bs[128*32];
  __shared__ int labR[128], labC[128];
  __shared__ float sMean[128], sTpp[128], sTnm[128];

  const int tid  = threadIdx.x;
  const int bx   = blockIdx.x;   // col block
  const int by   = blockIdx.y;   // row block
  const int lane = tid & 63;
  const int wave = tid >> 6;
  const int m0   = (wave >> 1) * 64;   // wave's row half of tile
  const int n0   = (wave & 1) * 64;    // wave's col half
  const int quad = lane >> 4;
  const int l15  = lane & 15;

  if (tid < 128){
    labR[tid] = labels[by*128 + tid];
    if (PASS == 2){
      int R = by*128 + tid;
      unsigned up = row_minpos[R], un = row_maxneg[R];
      float mp = (up == 0xFFFFFFFFu) ? 1.0e9f : decf(up);   // BIG like reference
      float mn = (un == 0u)          ? -1.0e9f : decf(un);
      sMean[tid] = (row_sum[R] * (1.0f/(float)NB) + 0.5f*(mp+mn)) * 0.5f;
      sTpp[tid]  = mn + 0.1f;   // pp: sim < max_neg + MARGIN
      sTnm[tid]  = mp - 0.1f;   // nm: sim > min_pos - MARGIN
    }
  } else {
    labC[tid-128] = labels[bx*128 + (tid-128)];
  }

  // staging: wave w owns rows [w*32, w*32+32) of both A and B tiles,
  // as 2 chunks of 16 rows; lane l -> row l/4, col (l%4)*8 (byte off = 16*l)
  const int srow = lane >> 2;
  const int scol = (lane & 3) * 8;
  const unsigned short* aseg = fb + (size_t)(by*128 + wave*32 + srow) * ND + scol;
  const unsigned short* bseg = fb + (size_t)(bx*128 + wave*32 + srow) * ND + scol;
  unsigned short* abase = &As[(wave*32) * 32];
  unsigned short* bbase = &Bs[(wave*32) * 32];

  f32x4 acc[4][4];
#pragma unroll
  for (int i=0;i<4;++i)
#pragma unroll
    for (int j=0;j<4;++j) acc[i][j] = (f32x4){0.f,0.f,0.f,0.f};

  for (int k0 = 0; k0 < ND; k0 += 32){
    __syncthreads();   // previous iter's LDS reads done (iter 0: label/stat writes)
#pragma unroll
    for (int c = 0; c < 2; ++c){
      gl2lds16(aseg + k0 + c*16*ND, abase + c*16*32);
      gl2lds16(bseg + k0 + c*16*ND, bbase + c*16*32);
    }
    __syncthreads();   // compiler drains vmcnt before barrier

    bf16x8 af[4], bfr[4];
#pragma unroll
    for (int s = 0; s < 4; ++s){
      af[s]  = __builtin_bit_cast(bf16x8, *(const u16x8*)&As[(m0 + s*16 + l15)*32 + quad*8]);
      bfr[s] = __builtin_bit_cast(bf16x8, *(const u16x8*)&Bs[(n0 + s*16 + l15)*32 + quad*8]);
    }
#pragma unroll
    for (int sm=0;sm<4;++sm)
#pragma unroll
      for (int sn=0;sn<4;++sn)
        acc[sm][sn] = __builtin_amdgcn_mfma_f32_16x16x32_bf16(af[sm], bfr[sn], acc[sm][sn], 0, 0, 0);
  }

  // epilogue. C/D layout: col = lane&15, row = quad*4 + reg (per 16x16 subtile)
  int lc[4];
#pragma unroll
  for (int sn=0;sn<4;++sn) lc[sn] = labC[n0 + sn*16 + l15];

#pragma unroll
  for (int sm=0;sm<4;++sm){
#pragma unroll
    for (int reg=0;reg<4;++reg){
      const int rl = m0 + sm*16 + quad*4 + reg;   // local row in tile
      const int lr = labR[rl];

      if (PASS == 1){
        float s = 0.f, mp = 3.0e38f, mn = -3.0e38f;
#pragma unroll
        for (int sn=0;sn<4;++sn){
          const float v = acc[sm][sn][reg];
          s += v;
          if (lr == lc[sn]){ if (v < 0.99999f) mp = fminf(mp, v); }
          else             { mn = fmaxf(mn, v); }
        }
#pragma unroll
        for (int o=1;o<16;o<<=1){
          s  += __shfl_xor(s, o, 64);
          mp  = fminf(mp, __shfl_xor(mp, o, 64));
          mn  = fmaxf(mn, __shfl_xor(mn, o, 64));
        }
        if (l15 == 0){
          int R = by*128 + rl;
          atomicAdd(&row_sum[R], s);
          if (mp <  1.0e38f) atomicMin(&row_minpos[R], encf(mp));
          if (mn > -1.0e38f) atomicMax(&row_maxneg[R], encf(mn));
        }
      } else {
        const float mean_ = sMean[rl], tpp = sTpp[rl], tnm = sTnm[rl];
        float sg = 0.f, fps = 0.f, fns = 0.f;
#pragma unroll
        for (int sn=0;sn<4;++sn){
          const float v = acc[sm][sn][reg];
          if (lr != lc[sn]){
            float d = v - mean_; sg += d*d;
            if (v > tnm) fns += __expf((v - 0.5f) * 40.0f);
          } else if (v < 0.99999f && v < tpp){
            fps += __expf(-(v - 0.5f) * 2.0f);
          }
        }
#pragma unroll
        for (int o=1;o<16;o<<=1){
          sg  += __shfl_xor(sg,  o, 64);
          fps += __shfl_xor(fps, o, 64);
          fns += __shfl_xor(fns, o, 64);
        }
        if (l15 == 0){
          int R = by*128 + rl;
          atomicAdd(&row_sigma[R], sg);
          atomicAdd(&row_fp[R], fps);
          atomicAdd(&row_fn[R], fns);
        }
      }
    }
  }
}

__global__ __launch_bounds__(1024) void finalize(const unsigned* row_minpos, const unsigned* row_maxneg,
                                                 const float* row_sigma, const float* row_fp,
                                                 const float* row_fn, float* out){
  const int tid = threadIdx.x;
  float local = 0.f;
  for (int r = tid; r < NB; r += 1024){
    bool has_pos = (row_minpos[r] != 0xFFFFFFFFu);
    bool has_neg = (row_maxneg[r] != 0u);
    float fps = row_fp[r], fns = row_fn[r];
    if (has_pos && has_neg && fps > 0.f && fns > 0.f){
      local += logf(1.f + fps) + logf(1.f + fns) + 0.1f * row_sigma[r];
    }
  }
#pragma unroll
  for (int o=1;o<64;o<<=1) local += __shfl_xor(local, o, 64);
  __shared__ float red[16];
  if ((tid & 63) == 0) red[tid >> 6] = local;
  __syncthreads();
  if (tid == 0){
    float t = 0.f;
#pragma unroll
    for (int i=0;i<16;++i) t += red[i];
    out[0] = t * (1.0f/(float)NB);
  }
}

extern "C" void kernel_launch(void* const* d_in, const int* in_sizes, int n_in,
                              void* d_out, int out_size, void* d_ws, size_t ws_size,
                              hipStream_t stream) {
  (void)in_sizes; (void)n_in; (void)out_size; (void)ws_size;
  const float* feats  = (const float*)d_in[0];
  const int*   labels = (const int*)d_in[1];
  float* out = (float*)d_out;

  // ws layout: 6 row-stat arrays (96KB) then bf16 feats (4MB)
  float*    row_sum    = (float*)d_ws;
  unsigned* row_minpos = (unsigned*)(row_sum + NB);
  unsigned* row_maxneg = row_minpos + NB;
  float*    row_sigma  = (float*)(row_maxneg + NB);
  float*    row_fp     = row_sigma + NB;
  float*    row_fn     = row_fp + NB;
  unsigned short* fb   = (unsigned short*)(row_fn + NB);

  convert_init<<<dim3((NB*ND/8)/256), dim3(256), 0, stream>>>(feats, fb, row_sum, row_minpos,
                                                              row_maxneg, row_sigma, row_fp, row_fn);
  dim3 grid(NB/128, NB/128);
  dbml_gemm<1><<<grid, dim3(256), 0, stream>>>(fb, labels, row_sum, row_minpos, row_maxneg,
                                               row_sigma, row_fp, row_fn);
  dbml_gemm<2><<<grid, dim3(256), 0, stream>>>(fb, labels, row_sum, row_minpos, row_maxneg,
                                               row_sigma, row_fp, row_fn);
  finalize<<<1, 1024, 0, stream>>>(row_minpos, row_maxneg, row_sigma, row_fp, row_fn, out);
}